// Round 3
// baseline (1528.611 us; speedup 1.0000x reference)
//
#include <hip/hip_runtime.h>

#define T_STEPS 1024
#define BATCH   64
#define NIN     32
#define NH      256
#define NOUT    16

typedef __attribute__((ext_vector_type(8))) _Float16 half8;
typedef __attribute__((ext_vector_type(4))) _Float16 half4;
typedef __attribute__((ext_vector_type(4))) float    f32x4;

__device__ __forceinline__ float fast_tanh(float x) {
  // tanh(x) = 1 - 2/(exp2(2*log2e*x)+1); exp2->inf/0 gives correct +-1 tails
  float e = __builtin_amdgcn_exp2f(x * 2.8853900817779268f);
  return 1.0f - 2.0f * __builtin_amdgcn_rcpf(e + 1.0f);
}

// LDS layout (round-2, conflict-verified): rlds[buf][m][...] ushort, row
// stride 320 (40 blocks of 8); element n at blk=(n>>3)^(m&7), j=n&7;
// u (k=256..287) at blk=(32+q)^(m&7).
#define ROW 320
#define BUFSZ (16 * 320)

// Round-5/6 bisect (round-5 hit an infra failure, resubmitted unchanged):
// 4 waves x 64 n-cols (mechanical translation of the proven 8x32 kernel;
// per-SIMD MFMA distribution identical at 44/36/36/36), with round-3's
// EXACT z path (wave 0 owns all 8 Wout kt), store ordering (x/z stores
// before publish) and prefetch position (after poll). The round-4
// z-distribution machinery (zpart reduce) is deleted pending bisection of
// the 468-absmax states corruption.
// Sync protocol unchanged: single ballot poll on 4 flags, no s_barrier,
// lgkmcnt(0) drain before flag publish.

__global__ __launch_bounds__(256, 1)
void RecurrentNetwork_19628000543215_kernel(
    const float* __restrict__ inputs,  // [T][B][NIN]
    const float* __restrict__ noise,   // [T][B][NH]
    const float* __restrict__ x0,      // [B][NH]
    const float* __restrict__ Win,     // [NIN][NH]
    const float* __restrict__ Wrec,    // [NH][NH]
    const float* __restrict__ brec,    // [NH]
    const float* __restrict__ Wout,    // [NH][NOUT]
    const float* __restrict__ bout,    // [NOUT]
    float* __restrict__ out)           // outputs [T][B][NOUT] ++ states [T][B][NH]
{
  __shared__ alignas(16) unsigned short rlds[2 * BUFSZ];
  __shared__ int prodf[4];
  volatile int* vflags = (volatile int*)prodf;

  const int g   = blockIdx.x;       // batch group: batches [16g, 16g+16)
  const int tid = threadIdx.x;
  const int w   = tid >> 6;         // wave 0..3: owns n-columns [64w, 64w+64)
  const int l   = tid & 63;
  const int m   = l & 15;           // batch-in-group (B col / C col)
  const int q   = l >> 4;           // quad
  const int b   = 16 * g + m;       // global batch
  const int mx  = m & 7;            // LDS swizzle key

  float* outz = out;
  float* outx = out + (size_t)T_STEPS * BATCH * NOUT;

  if (tid < 4) prodf[tid] = 0;

  // ---- weights -> persistent register A-frags, ALPHA pre-folded ----
  // A-frag (16x16x32): row = lane&15, k = (lane>>4)*8 + j; lane->k map only
  // has to MATCH the r/u LDS layout (contraction is permutation-invariant).
  half8 wr[4][9];                   // kt 0..7 = 0.1*Wrec^T, kt 8 = 0.1*Win^T
  #pragma unroll
  for (int nt = 0; nt < 4; ++nt) {
    const int n = 64 * w + 16 * nt + m;
    #pragma unroll
    for (int kt = 0; kt < 9; ++kt) {
      #pragma unroll
      for (int j = 0; j < 8; ++j) {
        const int k = 32 * kt + 8 * q + j;
        const float v = (kt < 8) ? Wrec[(size_t)k * NH + n]
                                 : Win[(size_t)(k - 256) * NH + n];
        wr[nt][kt][j] = (_Float16)(0.1f * v);
      }
    }
  }
  half8 wo[8];                      // Wout^T A-frags (z-tile), UNSCALED
  if (w == 0) {
    #pragma unroll
    for (int kt = 0; kt < 8; ++kt)
      #pragma unroll
      for (int j = 0; j < 8; ++j)
        wo[kt][j] = (_Float16)Wout[(size_t)(32 * kt + 8 * q + j) * NOUT + m];
  }

  f32x4 brecs[4], x[4];
  #pragma unroll
  for (int nt = 0; nt < 4; ++nt) {
    const int n0 = 64 * w + 16 * nt + 4 * q;
    brecs[nt] = 0.1f * (*(const f32x4*)(brec + n0));
    x[nt]     = *(const f32x4*)(x0 + (size_t)b * NH + n0);
  }
  const f32x4 bout4 = *(const f32x4*)(bout + 4 * q);

  // ---- preloop: r_{-1}=tanh(x0), u_0 -> buf0; q_0 -> regs ----
  #pragma unroll
  for (int nt = 0; nt < 4; ++nt) {
    const int n0 = 64 * w + 16 * nt + 4 * q;
    half4 r;
    r.x = (_Float16)fast_tanh(x[nt].x);
    r.y = (_Float16)fast_tanh(x[nt].y);
    r.z = (_Float16)fast_tanh(x[nt].z);
    r.w = (_Float16)fast_tanh(x[nt].w);
    const int blk = (n0 >> 3) ^ mx;
    *(half4*)&rlds[m * ROW + blk * 8 + (n0 & 7)] = r;
  }
  if (w == 1) {
    const float* up = inputs + (size_t)b * NIN + 8 * q;   // t = 0
    const f32x4 ua = *(const f32x4*)up;
    const f32x4 ub = *(const f32x4*)(up + 4);
    half8 uu;
    uu[0]=(_Float16)ua.x; uu[1]=(_Float16)ua.y; uu[2]=(_Float16)ua.z; uu[3]=(_Float16)ua.w;
    uu[4]=(_Float16)ub.x; uu[5]=(_Float16)ub.y; uu[6]=(_Float16)ub.z; uu[7]=(_Float16)ub.w;
    const int blk = (32 + q) ^ mx;
    *(half8*)&rlds[m * ROW + blk * 8] = uu;
  }
  f32x4 qv[4];
  #pragma unroll
  for (int nt = 0; nt < 4; ++nt)
    qv[nt] = *(const f32x4*)(noise + (size_t)b * NH + 64 * w + 16 * nt + 4 * q);  // q_0
  __syncthreads();

  int myfl = 0;                     // last-seen prodf[l&3]

  // ---- time loop ----
  #pragma unroll 1
  for (int t = 0; t < T_STEPS; ++t) {
    const int rb = (t & 1) * BUFSZ;
    const int wb = BUFSZ - rb;
    const int tn = (t + 1 < T_STEPS) ? t + 1 : T_STEPS - 1;

    // single poll point: all producers must have written step t-1
    while (__ballot(myfl >= t) != ~0ull) myfl = vflags[l & 3];
    asm volatile("" ::: "memory");  // no LDS reads hoisted above the poll

    f32x4 ua, ub;                   // wave 1: u_{t+1} load issued early
    if (w == 1) {
      const float* up = inputs + ((size_t)tn * BATCH + b) * NIN + 8 * q;
      ua = *(const f32x4*)up;
      ub = *(const f32x4*)(up + 4);
    }
    // q_{t+1} prefetch (consumed AFTER next step's K-loop => ~1.5 steps slack)
    f32x4 qn[4];
    #pragma unroll
    for (int nt = 0; nt < 4; ++nt)
      qn[nt] = *(const f32x4*)(noise + ((size_t)tn * BATCH + b) * NH + 64 * w + 16 * nt + 4 * q);

    // acc = 0.1*brec + r_{t-1}@(0.1*Wrec) + u_t@(0.1*Win)   [q_t added later]
    f32x4 acc[4];
    acc[0] = brecs[0]; acc[1] = brecs[1]; acc[2] = brecs[2]; acc[3] = brecs[3];
    f32x4 zac = bout4;              // z_{t-1} = bout + r_{t-1}@Wout (wave 0)

    #pragma unroll
    for (int kt = 0; kt < 9; ++kt) {
      const int blk = (4 * kt + q) ^ mx;
      const half8 bf = *(const half8*)&rlds[rb + m * ROW + blk * 8];
      acc[0] = __builtin_amdgcn_mfma_f32_16x16x32_f16(wr[0][kt], bf, acc[0], 0, 0, 0);
      acc[1] = __builtin_amdgcn_mfma_f32_16x16x32_f16(wr[1][kt], bf, acc[1], 0, 0, 0);
      acc[2] = __builtin_amdgcn_mfma_f32_16x16x32_f16(wr[2][kt], bf, acc[2], 0, 0, 0);
      acc[3] = __builtin_amdgcn_mfma_f32_16x16x32_f16(wr[3][kt], bf, acc[3], 0, 0, 0);
      if (w == 0 && kt < 8)
        zac = __builtin_amdgcn_mfma_f32_16x16x32_f16(wo[kt], bf, zac, 0, 0, 0);
    }

    // x_t = 0.9*x_{t-1} + acc + q_t ; store states[t]
    #pragma unroll
    for (int nt = 0; nt < 4; ++nt) {
      x[nt] = 0.9f * x[nt] + acc[nt] + qv[nt];
      const int n0 = 64 * w + 16 * nt + 4 * q;
      *(f32x4*)(outx + ((size_t)t * BATCH + b) * NH + n0) = x[nt];
    }

    if (w == 0 && t > 0)            // store z_{t-1} (fire-and-forget)
      *(f32x4*)(outz + ((size_t)(t - 1) * BATCH + b) * NOUT + 4 * q) = zac;

    // r_t = tanh(x_t) -> fp16 -> buf[(t+1)&1]
    #pragma unroll
    for (int nt = 0; nt < 4; ++nt) {
      const int n0 = 64 * w + 16 * nt + 4 * q;
      half4 r;
      r.x = (_Float16)fast_tanh(x[nt].x);
      r.y = (_Float16)fast_tanh(x[nt].y);
      r.z = (_Float16)fast_tanh(x[nt].z);
      r.w = (_Float16)fast_tanh(x[nt].w);
      const int blk = (n0 >> 3) ^ mx;
      *(half4*)&rlds[wb + m * ROW + blk * 8 + (n0 & 7)] = r;
    }

    if (w == 1) {                   // stage u_{t+1}
      half8 uu;
      uu[0]=(_Float16)ua.x; uu[1]=(_Float16)ua.y; uu[2]=(_Float16)ua.z; uu[3]=(_Float16)ua.w;
      uu[4]=(_Float16)ub.x; uu[5]=(_Float16)ub.y; uu[6]=(_Float16)ub.z; uu[7]=(_Float16)ub.w;
      const int blk = (32 + q) ^ mx;
      *(half8*)&rlds[wb + m * ROW + blk * 8] = uu;
    }

    qv[0] = qn[0]; qv[1] = qn[1]; qv[2] = qn[2]; qv[3] = qn[3];   // q_{t+1} now owned

    // publish: data drained (lgkm in-order) THEN flag
    asm volatile("s_waitcnt lgkmcnt(0)" ::: "memory");
    if (l == 0) vflags[w] = t + 1;
    myfl = vflags[l & 3];           // early re-read for next step's poll
  }

  // ---- epilogue: z_{T-1} from r_{T-1} (in buf0 after t=1023) ----
  if (w == 0) {
    while (__ballot(myfl >= T_STEPS) != ~0ull) myfl = vflags[l & 3];
    asm volatile("" ::: "memory");
    f32x4 zac = bout4;
    #pragma unroll
    for (int kt = 0; kt < 8; ++kt) {
      const int blk = (4 * kt + q) ^ mx;
      const half8 bf = *(const half8*)&rlds[m * ROW + blk * 8];
      zac = __builtin_amdgcn_mfma_f32_16x16x32_f16(wo[kt], bf, zac, 0, 0, 0);
    }
    *(f32x4*)(outz + ((size_t)(T_STEPS - 1) * BATCH + b) * NOUT + 4 * q) = zac;
  }
}

extern "C" void kernel_launch(void* const* d_in, const int* in_sizes, int n_in,
                              void* d_out, int out_size, void* d_ws, size_t ws_size,
                              hipStream_t stream) {
  (void)in_sizes; (void)n_in; (void)out_size; (void)d_ws; (void)ws_size;
  RecurrentNetwork_19628000543215_kernel<<<dim3(4), dim3(256), 0, stream>>>(
      (const float*)d_in[0],   // inputs
      (const float*)d_in[1],   // noise
      (const float*)d_in[2],   // x0
      (const float*)d_in[3],   // Win
      (const float*)d_in[4],   // Wrec
      (const float*)d_in[5],   // brec
      (const float*)d_in[6],   // Wout
      (const float*)d_in[7],   // bout
      (float*)d_out);
}